// Round 1
// baseline (399.424 us; speedup 1.0000x reference)
//
#include <hip/hip_runtime.h>
#include <hip/hip_bf16.h>
#include <stdint.h>

#define S_LEN 2048
#define D_MODEL 768
#define N_HEADS_ 12
#define D_K_ 64
#define BATCH 2
#define M_TOT (BATCH * S_LEN) /* 4096 */

typedef __attribute__((ext_vector_type(8))) short short8;
typedef __attribute__((ext_vector_type(4))) float f32x4;
typedef __attribute__((ext_vector_type(2))) unsigned int uint2v;

__device__ inline short f2bf(float f) {
  union { float f; uint32_t u; } v; v.f = f;
  uint32_t r = v.u + 0x7fffu + ((v.u >> 16) & 1u);
  return (short)(r >> 16);
}

__device__ inline f32x4 mfma16(short8 a, short8 b, f32x4 c) {
  return __builtin_amdgcn_mfma_f32_16x16x32_bf16(a, b, c, 0, 0, 0);
}

// ---------------------------------------------------------------------------
// 1) Weight transpose + bf16 cast: WT[n][k] = W[k][n]
// ---------------------------------------------------------------------------
__global__ __launch_bounds__(256) void transpose_w_kernel(const float* __restrict__ W,
                                                          short* __restrict__ WT) {
  __shared__ float t[32][33];
  int x = threadIdx.x, y = threadIdx.y;
  int nb = blockIdx.x * 32, kb = blockIdx.y * 32;
#pragma unroll
  for (int j = 0; j < 4; ++j)
    t[y + 8 * j][x] = W[(kb + y + 8 * j) * D_MODEL + nb + x];
  __syncthreads();
#pragma unroll
  for (int j = 0; j < 4; ++j)
    WT[(nb + y + 8 * j) * D_MODEL + kb + x] = f2bf(t[x][y + 8 * j]);
}

// ---------------------------------------------------------------------------
// 2) Projections: out = X @ W for Q,K,V (blockIdx.z selects).
//    Q,K stored [B,H,S,64]; V stored transposed [B,H,64,S].
// ---------------------------------------------------------------------------
__global__ __launch_bounds__(256) void proj_kernel(
    const float* __restrict__ Xq, const float* __restrict__ Xk, const float* __restrict__ Xv,
    const short* __restrict__ WTall,
    short* __restrict__ Qo, short* __restrict__ Ko, short* __restrict__ Vo) {
  int which = blockIdx.z;
  const float* X = which == 0 ? Xq : (which == 1 ? Xk : Xv);
  const short* WT = WTall + (size_t)which * D_MODEL * D_MODEL;
  int mbase = blockIdx.y * 64, nbase = blockIdx.x * 64;
  __shared__ short As[64][40];
  __shared__ short Bs[64][40];
  int tid = threadIdx.x;
  int w = tid >> 6, lane = tid & 63, r = lane & 15, g = lane >> 4;
  int lrow = tid >> 2, lcol = (tid & 3) * 8;
  int wm = (w & 1) * 32, wn = (w >> 1) * 32;
  f32x4 acc[2][2] = {};
  for (int kk = 0; kk < D_MODEL; kk += 32) {
    const float* xp = X + (size_t)(mbase + lrow) * D_MODEL + kk + lcol;
    float4 f0 = *(const float4*)xp;
    float4 f1 = *(const float4*)(xp + 4);
    short8 av;
    av[0] = f2bf(f0.x); av[1] = f2bf(f0.y); av[2] = f2bf(f0.z); av[3] = f2bf(f0.w);
    av[4] = f2bf(f1.x); av[5] = f2bf(f1.y); av[6] = f2bf(f1.z); av[7] = f2bf(f1.w);
    short8 bv = *(const short8*)(WT + (size_t)(nbase + lrow) * D_MODEL + kk + lcol);
    *(short8*)&As[lrow][lcol] = av;
    *(short8*)&Bs[lrow][lcol] = bv;
    __syncthreads();
    short8 a0 = *(short8*)&As[wm + r][g * 8];
    short8 a1 = *(short8*)&As[wm + 16 + r][g * 8];
    short8 b0 = *(short8*)&Bs[wn + r][g * 8];
    short8 b1 = *(short8*)&Bs[wn + 16 + r][g * 8];
    acc[0][0] = mfma16(a0, b0, acc[0][0]);
    acc[0][1] = mfma16(a0, b1, acc[0][1]);
    acc[1][0] = mfma16(a1, b0, acc[1][0]);
    acc[1][1] = mfma16(a1, b1, acc[1][1]);
    __syncthreads();
  }
#pragma unroll
  for (int i = 0; i < 2; ++i)
#pragma unroll
    for (int j = 0; j < 2; ++j)
#pragma unroll
      for (int reg = 0; reg < 4; ++reg) {
        int m = mbase + wm + i * 16 + g * 4 + reg;
        int n = nbase + wn + j * 16 + r;
        int b = m >> 11, s = m & 2047, h = n >> 6, d = n & 63;
        short v = f2bf(acc[i][j][reg]);
        if (which == 0)
          Qo[(((size_t)b * N_HEADS_ + h) * S_LEN + s) * D_K_ + d] = v;
        else if (which == 1)
          Ko[(((size_t)b * N_HEADS_ + h) * S_LEN + s) * D_K_ + d] = v;
        else
          Vo[(((size_t)b * N_HEADS_ + h) * D_K_ + d) * S_LEN + s] = v;
      }
}

// ---------------------------------------------------------------------------
// 3) Flash attention: 1 wave = 16 q rows; 32-key chunks; online softmax.
//    S^T = K * Q^T  (D: col=lane&15 -> q, row -> key), then P @ V via LDS bounce.
// ---------------------------------------------------------------------------
__global__ __launch_bounds__(256) void attn_kernel(
    const short* __restrict__ Qg, const short* __restrict__ Kg,
    const short* __restrict__ Vt, short* __restrict__ ctx) {
  int bh = blockIdx.y;
  int b = bh / N_HEADS_, h = bh % N_HEADS_;
  int tid = threadIdx.x;
  int w = tid >> 6, lane = tid & 63, r = lane & 15, g = lane >> 4;
  int qbase = (blockIdx.x * 4 + w) * 16;
  const short* qp = Qg + (size_t)bh * S_LEN * D_K_;
  const short* kp = Kg + (size_t)bh * S_LEN * D_K_;
  const short* vp = Vt + (size_t)bh * D_K_ * S_LEN;
  __shared__ short pbuf[4][16][40];

  short8 qf[2];
  qf[0] = *(const short8*)(qp + (size_t)(qbase + r) * D_K_ + g * 8);
  qf[1] = *(const short8*)(qp + (size_t)(qbase + r) * D_K_ + 32 + g * 8);

  f32x4 o[4] = {};
  float m_run = -1e30f, l_run = 0.f;

  for (int kc = 0; kc < S_LEN; kc += 32) {
    short8 ka[2][2];
#pragma unroll
    for (int s2 = 0; s2 < 2; ++s2) {
      ka[s2][0] = *(const short8*)(kp + (size_t)(kc + s2 * 16 + r) * D_K_ + g * 8);
      ka[s2][1] = *(const short8*)(kp + (size_t)(kc + s2 * 16 + r) * D_K_ + 32 + g * 8);
    }
    f32x4 st[2] = {};
    st[0] = mfma16(ka[0][0], qf[0], st[0]);
    st[0] = mfma16(ka[0][1], qf[1], st[0]);
    st[1] = mfma16(ka[1][0], qf[0], st[1]);
    st[1] = mfma16(ka[1][1], qf[1], st[1]);

    float p[8];
    float cm = -1e30f;
#pragma unroll
    for (int s2 = 0; s2 < 2; ++s2)
#pragma unroll
      for (int j = 0; j < 4; ++j) {
        float v = st[s2][j] * 0.125f;
        p[s2 * 4 + j] = v;
        cm = fmaxf(cm, v);
      }
    cm = fmaxf(cm, __shfl_xor(cm, 16));
    cm = fmaxf(cm, __shfl_xor(cm, 32));
    float m_new = fmaxf(m_run, cm);
    float alpha = __expf(m_run - m_new);
    float csum = 0.f;
#pragma unroll
    for (int i = 0; i < 8; ++i) {
      p[i] = __expf(p[i] - m_new);
      csum += p[i];
    }
    csum += __shfl_xor(csum, 16);
    csum += __shfl_xor(csum, 32);
    l_run = l_run * alpha + csum;
    m_run = m_new;
#pragma unroll
    for (int reg = 0; reg < 4; ++reg) {
      float av = __shfl(alpha, g * 4 + reg);
      o[0][reg] *= av; o[1][reg] *= av; o[2][reg] *= av; o[3][reg] *= av;
    }
    // P^T (row=key in regs) -> LDS as P[q][k], then reload as A-fragments
#pragma unroll
    for (int s2 = 0; s2 < 2; ++s2) {
      uint2v u;
      u[0] = (uint32_t)(uint16_t)f2bf(p[s2 * 4 + 0]) |
             ((uint32_t)(uint16_t)f2bf(p[s2 * 4 + 1]) << 16);
      u[1] = (uint32_t)(uint16_t)f2bf(p[s2 * 4 + 2]) |
             ((uint32_t)(uint16_t)f2bf(p[s2 * 4 + 3]) << 16);
      *(uint2v*)&pbuf[w][r][s2 * 16 + g * 4] = u;
    }
    short8 pa = *(short8*)&pbuf[w][r][g * 8];
#pragma unroll
    for (int t = 0; t < 4; ++t) {
      short8 vb = *(const short8*)(vp + (size_t)(t * 16 + r) * S_LEN + kc + g * 8);
      o[t] = mfma16(pa, vb, o[t]);
    }
  }
#pragma unroll
  for (int reg = 0; reg < 4; ++reg) {
    float lq = __shfl(l_run, g * 4 + reg);
    float inv = 1.0f / lq;
    int m = b * S_LEN + qbase + g * 4 + reg;
#pragma unroll
    for (int t = 0; t < 4; ++t)
      ctx[(size_t)m * D_MODEL + h * D_K_ + t * 16 + r] = f2bf(o[t][reg] * inv);
  }
}

// ---------------------------------------------------------------------------
// 4) out = LayerNorm(ctx @ Wo + residual). One block = 16 full rows.
//    4 waves x 192 cols; 12 n-tiles per wave.
// ---------------------------------------------------------------------------
__global__ __launch_bounds__(256) void outln_kernel(
    const short* __restrict__ ctx, const short* __restrict__ WoT,
    const float* __restrict__ resid, float* __restrict__ out) {
  int mbase = blockIdx.x * 16;
  int tid = threadIdx.x;
  int w = tid >> 6, lane = tid & 63, r = lane & 15, g = lane >> 4;
  f32x4 acc[12] = {};
  for (int kk = 0; kk < D_MODEL; kk += 32) {
    short8 a = *(const short8*)(ctx + (size_t)(mbase + r) * D_MODEL + kk + g * 8);
#pragma unroll
    for (int j = 0; j < 12; ++j) {
      int n = w * 192 + j * 16 + r;
      short8 bv = *(const short8*)(WoT + (size_t)n * D_MODEL + kk + g * 8);
      acc[j] = mfma16(a, bv, acc[j]);
    }
  }
  __shared__ float redS[16][4];
  __shared__ float redQ[16][4];
  float ps[4], pq[4];
#pragma unroll
  for (int reg = 0; reg < 4; ++reg) {
    int m = mbase + g * 4 + reg;
    float s = 0.f, q = 0.f;
#pragma unroll
    for (int j = 0; j < 12; ++j) {
      float v = acc[j][reg] + resid[(size_t)m * D_MODEL + w * 192 + j * 16 + r];
      acc[j][reg] = v;
      s += v;
      q += v * v;
    }
    ps[reg] = s; pq[reg] = q;
  }
#pragma unroll
  for (int reg = 0; reg < 4; ++reg) {
    float s = ps[reg], q = pq[reg];
    s += __shfl_xor(s, 1); q += __shfl_xor(q, 1);
    s += __shfl_xor(s, 2); q += __shfl_xor(q, 2);
    s += __shfl_xor(s, 4); q += __shfl_xor(q, 4);
    s += __shfl_xor(s, 8); q += __shfl_xor(q, 8);
    if (r == 0) { redS[g * 4 + reg][w] = s; redQ[g * 4 + reg][w] = q; }
  }
  __syncthreads();
#pragma unroll
  for (int reg = 0; reg < 4; ++reg) {
    int row = g * 4 + reg;
    float s = redS[row][0] + redS[row][1] + redS[row][2] + redS[row][3];
    float q = redQ[row][0] + redQ[row][1] + redQ[row][2] + redQ[row][3];
    float mu = s * (1.0f / 768.0f);
    float var = q * (1.0f / 768.0f) - mu * mu;
    float rstd = rsqrtf(var + 1e-5f);
    int m = mbase + row;
#pragma unroll
    for (int j = 0; j < 12; ++j)
      out[(size_t)m * D_MODEL + w * 192 + j * 16 + r] = (acc[j][reg] - mu) * rstd;
  }
}

// ---------------------------------------------------------------------------
extern "C" void kernel_launch(void* const* d_in, const int* in_sizes, int n_in,
                              void* d_out, int out_size, void* d_ws, size_t ws_size,
                              hipStream_t stream) {
  const float* xq = (const float*)d_in[0];
  const float* xk = (const float*)d_in[1];
  const float* xv = (const float*)d_in[2];
  const float* Wq = (const float*)d_in[3];
  const float* Wk = (const float*)d_in[4];
  const float* Wv = (const float*)d_in[5];
  const float* Wo = (const float*)d_in[6];
  float* out = (float*)d_out;

  char* ws = (char*)d_ws;
  const size_t WSZ = (size_t)D_MODEL * D_MODEL;          // 589824 elems
  const size_t QSZ = (size_t)M_TOT * D_MODEL;            // 3145728 elems
  short* WT = (short*)ws;                                // 4 weights, bf16
  short* Qb = (short*)(ws + 4 * WSZ * sizeof(short));
  short* Kb = Qb + QSZ;
  short* Vb = Kb + QSZ;
  short* Cx = Vb + QSZ;

  dim3 tb(32, 8);
  transpose_w_kernel<<<dim3(24, 24), tb, 0, stream>>>(Wq, WT);
  transpose_w_kernel<<<dim3(24, 24), tb, 0, stream>>>(Wk, WT + WSZ);
  transpose_w_kernel<<<dim3(24, 24), tb, 0, stream>>>(Wv, WT + 2 * WSZ);
  transpose_w_kernel<<<dim3(24, 24), tb, 0, stream>>>(Wo, WT + 3 * WSZ);

  proj_kernel<<<dim3(12, 64, 3), 256, 0, stream>>>(xq, xk, xv, WT, Qb, Kb, Vb);
  attn_kernel<<<dim3(32, 24), 256, 0, stream>>>(Qb, Kb, Vb, Cx);
  outln_kernel<<<dim3(256), 256, 0, stream>>>(Cx, WT + 3 * WSZ, xq, out);
}

// Round 2
// 289.196 us; speedup vs baseline: 1.3812x; 1.3812x over previous
//
#include <hip/hip_runtime.h>
#include <hip/hip_bf16.h>
#include <stdint.h>

#define S_LEN 2048
#define D_MODEL 768
#define NH 12
#define DK 64
#define BATCH 2
#define M_TOT (BATCH * S_LEN) /* 4096 */

typedef __attribute__((ext_vector_type(8))) short short8;
typedef __attribute__((ext_vector_type(4))) float f32x4;
typedef __attribute__((ext_vector_type(16))) float f32x16;

__device__ inline short f2bf(float f) {
  union { float f; uint32_t u; } v; v.f = f;
  uint32_t r = v.u + 0x7fffu + ((v.u >> 16) & 1u);
  return (short)(r >> 16);
}

__device__ inline f32x4 mfma16(short8 a, short8 b, f32x4 c) {
  return __builtin_amdgcn_mfma_f32_16x16x32_bf16(a, b, c, 0, 0, 0);
}
__device__ inline f32x16 mfma32(short8 a, short8 b, f32x16 c) {
  return __builtin_amdgcn_mfma_f32_32x32x16_bf16(a, b, c, 0, 0, 0);
}

__device__ inline void gl16(const void* g, void* l) {
  __builtin_amdgcn_global_load_lds(
      (const __attribute__((address_space(1))) unsigned*)g,
      (__attribute__((address_space(3))) unsigned*)l, 16, 0, 0);
}

__device__ inline unsigned cvtpk(float lo, float hi) {
  unsigned r;
  asm("v_cvt_pk_bf16_f32 %0, %1, %2" : "=v"(r) : "v"(lo), "v"(hi));
  return r;
}
__device__ inline void plswap(unsigned& a, unsigned& b) {
  asm("v_permlane32_swap_b32 %0, %1" : "+v"(a), "+v"(b));
}

// ---------------------------------------------------------------------------
// 1) Weight transpose + bf16 cast: WT[n][k] = W[k][n]
// ---------------------------------------------------------------------------
__global__ __launch_bounds__(256) void transpose_w_kernel(const float* __restrict__ W,
                                                          short* __restrict__ WT) {
  __shared__ float t[32][33];
  int x = threadIdx.x, y = threadIdx.y;
  int nb = blockIdx.x * 32, kb = blockIdx.y * 32;
#pragma unroll
  for (int j = 0; j < 4; ++j)
    t[y + 8 * j][x] = W[(kb + y + 8 * j) * D_MODEL + nb + x];
  __syncthreads();
#pragma unroll
  for (int j = 0; j < 4; ++j)
    WT[(nb + y + 8 * j) * D_MODEL + kb + x] = f2bf(t[x][y + 8 * j]);
}

// ---------------------------------------------------------------------------
// 2) Projections. Q scaled by 0.125*log2(e) (attn works in exp2 domain).
//    K stored XOR-swizzled [bh][s][d ^ ((s&7)<<3)]  (bank-conflict-free attn reads)
//    V stored transposed + swizzled [bh][d][s ^ ((d&7)<<3)]
// ---------------------------------------------------------------------------
__global__ __launch_bounds__(256) void proj_kernel(
    const float* __restrict__ Xq, const float* __restrict__ Xk, const float* __restrict__ Xv,
    const short* __restrict__ WTall,
    short* __restrict__ Qo, short* __restrict__ Ko, short* __restrict__ Vo) {
  int which = blockIdx.z;
  const float* X = which == 0 ? Xq : (which == 1 ? Xk : Xv);
  const short* WT = WTall + (size_t)which * D_MODEL * D_MODEL;
  int mbase = blockIdx.y * 64, nbase = blockIdx.x * 64;
  __shared__ short As[64][40];
  __shared__ short Bs[64][40];
  int tid = threadIdx.x;
  int w = tid >> 6, lane = tid & 63, r = lane & 15, g = lane >> 4;
  int lrow = tid >> 2, lcol = (tid & 3) * 8;
  int wm = (w & 1) * 32, wn = (w >> 1) * 32;
  f32x4 acc[2][2] = {};
  for (int kk = 0; kk < D_MODEL; kk += 32) {
    const float* xp = X + (size_t)(mbase + lrow) * D_MODEL + kk + lcol;
    float4 f0 = *(const float4*)xp;
    float4 f1 = *(const float4*)(xp + 4);
    short8 av;
    av[0] = f2bf(f0.x); av[1] = f2bf(f0.y); av[2] = f2bf(f0.z); av[3] = f2bf(f0.w);
    av[4] = f2bf(f1.x); av[5] = f2bf(f1.y); av[6] = f2bf(f1.z); av[7] = f2bf(f1.w);
    short8 bv = *(const short8*)(WT + (size_t)(nbase + lrow) * D_MODEL + kk + lcol);
    *(short8*)&As[lrow][lcol] = av;
    *(short8*)&Bs[lrow][lcol] = bv;
    __syncthreads();
    short8 a0 = *(short8*)&As[wm + r][g * 8];
    short8 a1 = *(short8*)&As[wm + 16 + r][g * 8];
    short8 b0 = *(short8*)&Bs[wn + r][g * 8];
    short8 b1 = *(short8*)&Bs[wn + 16 + r][g * 8];
    acc[0][0] = mfma16(a0, b0, acc[0][0]);
    acc[0][1] = mfma16(a0, b1, acc[0][1]);
    acc[1][0] = mfma16(a1, b0, acc[1][0]);
    acc[1][1] = mfma16(a1, b1, acc[1][1]);
    __syncthreads();
  }
#pragma unroll
  for (int i = 0; i < 2; ++i)
#pragma unroll
    for (int j = 0; j < 2; ++j)
#pragma unroll
      for (int reg = 0; reg < 4; ++reg) {
        int m = mbase + wm + i * 16 + g * 4 + reg;
        int n = nbase + wn + j * 16 + r;
        int b = m >> 11, s = m & 2047, h = n >> 6, d = n & 63;
        if (which == 0) {
          short v = f2bf(acc[i][j][reg] * 0.18033688f); // 1/8 * log2(e)
          Qo[(((size_t)b * NH + h) * S_LEN + s) * DK + d] = v;
        } else if (which == 1) {
          short v = f2bf(acc[i][j][reg]);
          Ko[(((size_t)b * NH + h) * S_LEN + s) * DK + (d ^ ((s & 7) << 3))] = v;
        } else {
          short v = f2bf(acc[i][j][reg]);
          Vo[(((size_t)b * NH + h) * DK + d) * S_LEN + (s ^ ((d & 7) << 3))] = v;
        }
      }
}

// ---------------------------------------------------------------------------
// 3) Flash attention, m214-style: 2 waves/block, 32 q-rows/wave, KVBLK=64,
//    32x32x16 MFMA, swapped QK^T (lane-local softmax rows, exp2 domain),
//    LDS-staged K/V (double-buffered, global_load_lds, counted vmcnt),
//    cvt_pk + permlane32_swap for in-register P->A-fragment, defer-max.
// ---------------------------------------------------------------------------
__global__ __launch_bounds__(128) void attn_kernel(
    const short* __restrict__ Qg, const short* __restrict__ Kg,
    const short* __restrict__ Vt, short* __restrict__ ctx) {
  __shared__ char K_lds[2][8192];
  __shared__ char V_lds[2][8192];
  int bh = blockIdx.y;
  int b = bh / NH, h = bh % NH;
  int tid = threadIdx.x;
  int w = tid >> 6, lane = tid & 63;
  int c32 = lane & 31, hi = lane >> 5;
  int qbase = blockIdx.x * 64 + w * 32;
  const short* qp = Qg + (size_t)bh * S_LEN * DK;
  const char* kp = (const char*)(Kg + (size_t)bh * S_LEN * DK);
  const char* vp = (const char*)(Vt + (size_t)bh * DK * S_LEN);

  // Q fragments (B-operand: lane holds Q[q=c32][k=kk*16+hi*8 .. +7])
  short8 qf[4];
#pragma unroll
  for (int kk = 0; kk < 4; ++kk)
    qf[kk] = *(const short8*)(qp + (size_t)(qbase + c32) * DK + kk * 16 + hi * 8);

  // --- staging: 8 global_load_lds per wave per tile (K 4KB + V 4KB) ---
#define STAGE(buf, kc)                                                          \
  {                                                                             \
    _Pragma("unroll") for (int j = 0; j < 4; ++j) {                             \
      int p = w * 4 + j;                                                        \
      gl16(kp + (size_t)(kc)*128 + p * 1024 + lane * 16, &K_lds[buf][p * 1024]);\
    }                                                                           \
    _Pragma("unroll") for (int j = 0; j < 4; ++j) {                             \
      int p = w * 4 + j;                                                        \
      int row = p * 8 + (lane >> 3);                                            \
      gl16(vp + (size_t)row * 4096 + (kc)*2 + (lane & 7) * 16,                  \
           &V_lds[buf][p * 1024]);                                              \
    }                                                                           \
  }

  STAGE(0, 0);

  f32x16 o0 = {}, o1 = {};
  float m_run = -30000.f, l_run = 0.f;
  int cur = 0;

  for (int t = 0; t < S_LEN / 64; ++t) {
    if (t < S_LEN / 64 - 1) {
      STAGE(cur ^ 1, (t + 1) * 64);
      asm volatile("s_waitcnt vmcnt(8)" ::: "memory"); // current tile done, prefetch in flight
    } else {
      asm volatile("s_waitcnt vmcnt(0)" ::: "memory");
    }
    __builtin_amdgcn_s_barrier();

    const char* kb = K_lds[cur];
    const char* vb = V_lds[cur];

    // QK^T (swapped): st = mfma(K, Q) -> lane holds col q=c32, 16 keys/subtile
    f32x16 st0 = {}, st1 = {};
#pragma unroll
    for (int kk = 0; kk < 4; ++kk) {
      int cb = kk * 32 + hi * 16;
      short8 k0 = *(const short8*)(kb + c32 * 128 + (cb ^ ((c32 & 7) << 4)));
      short8 k1 = *(const short8*)(kb + (32 + c32) * 128 + (cb ^ ((c32 & 7) << 4)));
      st0 = mfma32(k0, qf[kk], st0);
      st1 = mfma32(k1, qf[kk], st1);
    }

    // online softmax in exp2 domain (scale folded into Q)
    float cm = -30000.f;
#pragma unroll
    for (int i = 0; i < 16; ++i) cm = fmaxf(cm, fmaxf(st0[i], st1[i]));
    cm = fmaxf(cm, __shfl_xor(cm, 32));
    if (!__all(cm <= m_run + 8.0f)) { // defer-max: rescale only on real growth
      float m_new = fmaxf(m_run, cm);
      float al = __builtin_amdgcn_exp2f(m_run - m_new);
      l_run *= al;
      m_run = m_new;
#pragma unroll
      for (int r = 0; r < 16; ++r) {
        int ql = (r & 3) + 8 * (r >> 2) + 4 * hi;
        float ar = __shfl(al, ql);
        o0[r] *= ar;
        o1[r] *= ar;
      }
    }
    float csum = 0.f;
#pragma unroll
    for (int i = 0; i < 16; ++i) {
      st0[i] = __builtin_amdgcn_exp2f(st0[i] - m_run);
      st1[i] = __builtin_amdgcn_exp2f(st1[i] - m_run);
      csum += st0[i] + st1[i];
    }
    csum += __shfl_xor(csum, 32);
    l_run += csum;

    // P -> bf16 A-fragments in-register (cvt_pk + permlane32_swap), then PV
#pragma unroll
    for (int ks = 0; ks < 4; ++ks) {
      f32x16 P = (ks < 2) ? st0 : st1;
      int s8 = (ks & 1) * 8;
      unsigned A = cvtpk(P[s8 + 0], P[s8 + 1]);
      unsigned Bx = cvtpk(P[s8 + 4], P[s8 + 5]);
      unsigned C = cvtpk(P[s8 + 2], P[s8 + 3]);
      unsigned Dx = cvtpk(P[s8 + 6], P[s8 + 7]);
      plswap(A, Bx);
      plswap(C, Dx);
      union { unsigned u[4]; short8 s; } pu;
      pu.u[0] = A; pu.u[1] = C; pu.u[2] = Bx; pu.u[3] = Dx;
      int cb = ks * 32 + hi * 16;
      short8 v0 = *(const short8*)(vb + c32 * 128 + (cb ^ ((c32 & 7) << 4)));
      short8 v1 = *(const short8*)(vb + (32 + c32) * 128 + (cb ^ ((c32 & 7) << 4)));
      o0 = mfma32(pu.s, v0, o0);
      o1 = mfma32(pu.s, v1, o1);
    }

    __builtin_amdgcn_s_barrier();
    cur ^= 1;
  }

  // epilogue: normalize and write ctx[b*S+q][h*64 + d]
  size_t rowbase = (size_t)b * S_LEN + qbase;
#pragma unroll
  for (int r = 0; r < 16; ++r) {
    int ql = (r & 3) + 8 * (r >> 2) + 4 * hi;
    float linv = 1.0f / __shfl(l_run, ql);
    short* cp = ctx + (rowbase + ql) * D_MODEL + h * DK;
    cp[c32] = f2bf(o0[r] * linv);
    cp[32 + c32] = f2bf(o1[r] * linv);
  }
#undef STAGE
}

// ---------------------------------------------------------------------------
// 4) out = LayerNorm(ctx @ Wo + residual). One block = 16 full rows.
// ---------------------------------------------------------------------------
__global__ __launch_bounds__(256) void outln_kernel(
    const short* __restrict__ ctx, const short* __restrict__ WoT,
    const float* __restrict__ resid, float* __restrict__ out) {
  int mbase = blockIdx.x * 16;
  int tid = threadIdx.x;
  int w = tid >> 6, lane = tid & 63, r = lane & 15, g = lane >> 4;
  f32x4 acc[12] = {};
  for (int kk = 0; kk < D_MODEL; kk += 32) {
    short8 a = *(const short8*)(ctx + (size_t)(mbase + r) * D_MODEL + kk + g * 8);
#pragma unroll
    for (int j = 0; j < 12; ++j) {
      int n = w * 192 + j * 16 + r;
      short8 bv = *(const short8*)(WoT + (size_t)n * D_MODEL + kk + g * 8);
      acc[j] = mfma16(a, bv, acc[j]);
    }
  }
  __shared__ float redS[16][4];
  __shared__ float redQ[16][4];
  float ps[4], pq[4];
#pragma unroll
  for (int reg = 0; reg < 4; ++reg) {
    int m = mbase + g * 4 + reg;
    float s = 0.f, q = 0.f;
#pragma unroll
    for (int j = 0; j < 12; ++j) {
      float v = acc[j][reg] + resid[(size_t)m * D_MODEL + w * 192 + j * 16 + r];
      acc[j][reg] = v;
      s += v;
      q += v * v;
    }
    ps[reg] = s; pq[reg] = q;
  }
#pragma unroll
  for (int reg = 0; reg < 4; ++reg) {
    float s = ps[reg], q = pq[reg];
    s += __shfl_xor(s, 1); q += __shfl_xor(q, 1);
    s += __shfl_xor(s, 2); q += __shfl_xor(q, 2);
    s += __shfl_xor(s, 4); q += __shfl_xor(q, 4);
    s += __shfl_xor(s, 8); q += __shfl_xor(q, 8);
    if (r == 0) { redS[g * 4 + reg][w] = s; redQ[g * 4 + reg][w] = q; }
  }
  __syncthreads();
#pragma unroll
  for (int reg = 0; reg < 4; ++reg) {
    int row = g * 4 + reg;
    float s = redS[row][0] + redS[row][1] + redS[row][2] + redS[row][3];
    float q = redQ[row][0] + redQ[row][1] + redQ[row][2] + redQ[row][3];
    float mu = s * (1.0f / 768.0f);
    float var = q * (1.0f / 768.0f) - mu * mu;
    float rstd = rsqrtf(var + 1e-5f);
    int m = mbase + row;
#pragma unroll
    for (int j = 0; j < 12; ++j)
      out[(size_t)m * D_MODEL + w * 192 + j * 16 + r] = (acc[j][reg] - mu) * rstd;
  }
}

// ---------------------------------------------------------------------------
extern "C" void kernel_launch(void* const* d_in, const int* in_sizes, int n_in,
                              void* d_out, int out_size, void* d_ws, size_t ws_size,
                              hipStream_t stream) {
  const float* xq = (const float*)d_in[0];
  const float* xk = (const float*)d_in[1];
  const float* xv = (const float*)d_in[2];
  const float* Wq = (const float*)d_in[3];
  const float* Wk = (const float*)d_in[4];
  const float* Wv = (const float*)d_in[5];
  const float* Wo = (const float*)d_in[6];
  float* out = (float*)d_out;

  char* ws = (char*)d_ws;
  const size_t WSZ = (size_t)D_MODEL * D_MODEL;
  const size_t QSZ = (size_t)M_TOT * D_MODEL;
  short* WT = (short*)ws;
  short* Qb = (short*)(ws + 4 * WSZ * sizeof(short));
  short* Kb = Qb + QSZ;
  short* Vb = Kb + QSZ;
  short* Cx = Vb + QSZ;

  dim3 tb(32, 8);
  transpose_w_kernel<<<dim3(24, 24), tb, 0, stream>>>(Wq, WT);
  transpose_w_kernel<<<dim3(24, 24), tb, 0, stream>>>(Wk, WT + WSZ);
  transpose_w_kernel<<<dim3(24, 24), tb, 0, stream>>>(Wv, WT + 2 * WSZ);
  transpose_w_kernel<<<dim3(24, 24), tb, 0, stream>>>(Wo, WT + 3 * WSZ);

  proj_kernel<<<dim3(12, 64, 3), 256, 0, stream>>>(xq, xk, xv, WT, Qb, Kb, Vb);
  attn_kernel<<<dim3(32, 24), 128, 0, stream>>>(Qb, Kb, Vb, Cx);
  outln_kernel<<<dim3(256), 256, 0, stream>>>(Cx, WT + 3 * WSZ, xq, out);
}

// Round 3
// 269.514 us; speedup vs baseline: 1.4820x; 1.0730x over previous
//
#include <hip/hip_runtime.h>
#include <hip/hip_bf16.h>
#include <stdint.h>

#define S_LEN 2048
#define D_MODEL 768
#define NH 12
#define DK 64
#define BATCH 2
#define M_TOT (BATCH * S_LEN) /* 4096 */

typedef __attribute__((ext_vector_type(8))) short short8;
typedef __attribute__((ext_vector_type(4))) float f32x4;
typedef __attribute__((ext_vector_type(16))) float f32x16;

__device__ inline short f2bf(float f) {
  union { float f; uint32_t u; } v; v.f = f;
  uint32_t r = v.u + 0x7fffu + ((v.u >> 16) & 1u);
  return (short)(r >> 16);
}

__device__ inline f32x4 mfma16(short8 a, short8 b, f32x4 c) {
  return __builtin_amdgcn_mfma_f32_16x16x32_bf16(a, b, c, 0, 0, 0);
}
__device__ inline f32x16 mfma32(short8 a, short8 b, f32x16 c) {
  return __builtin_amdgcn_mfma_f32_32x32x16_bf16(a, b, c, 0, 0, 0);
}

__device__ inline void gl16(const void* g, void* l) {
  __builtin_amdgcn_global_load_lds(
      (const __attribute__((address_space(1))) unsigned*)g,
      (__attribute__((address_space(3))) unsigned*)l, 16, 0, 0);
}

__device__ inline unsigned cvtpk(float lo, float hi) {
  unsigned r;
  asm("v_cvt_pk_bf16_f32 %0, %1, %2" : "=v"(r) : "v"(lo), "v"(hi));
  return r;
}
__device__ inline void plswap(unsigned& a, unsigned& b) {
  asm("v_permlane32_swap_b32 %0, %1" : "+v"(a), "+v"(b));
}

// ---------------------------------------------------------------------------
// 1a) Weight transpose + bf16 cast (all 4 weights in one launch, z selects)
// ---------------------------------------------------------------------------
__global__ __launch_bounds__(256) void transpose_w_kernel(
    const float* __restrict__ Wq, const float* __restrict__ Wk,
    const float* __restrict__ Wv, const float* __restrict__ Wo,
    short* __restrict__ WT) {
  int z = blockIdx.z;
  const float* W = z == 0 ? Wq : (z == 1 ? Wk : (z == 2 ? Wv : Wo));
  short* O = WT + (size_t)z * D_MODEL * D_MODEL;
  __shared__ float t[32][33];
  int x = threadIdx.x, y = threadIdx.y;
  int nb = blockIdx.x * 32, kb = blockIdx.y * 32;
#pragma unroll
  for (int j = 0; j < 4; ++j)
    t[y + 8 * j][x] = W[(kb + y + 8 * j) * D_MODEL + nb + x];
  __syncthreads();
#pragma unroll
  for (int j = 0; j < 4; ++j)
    O[(nb + y + 8 * j) * D_MODEL + kb + x] = f2bf(t[x][y + 8 * j]);
}

// ---------------------------------------------------------------------------
// 1b) Activation cast fp32 -> bf16 (one pass; removes 12x fp32 re-fetch)
// ---------------------------------------------------------------------------
__global__ __launch_bounds__(256) void cast_x_kernel(
    const float* __restrict__ Xq, const float* __restrict__ Xk,
    const float* __restrict__ Xv, short* __restrict__ Xb) {
  int z = blockIdx.y;
  const float* X = z == 0 ? Xq : (z == 1 ? Xk : Xv);
  short* O = Xb + (size_t)z * M_TOT * D_MODEL;
  size_t i = ((size_t)blockIdx.x * 256 + threadIdx.x) * 8;
  float4 f0 = *(const float4*)(X + i);
  float4 f1 = *(const float4*)(X + i + 4);
  short8 v;
  v[0] = f2bf(f0.x); v[1] = f2bf(f0.y); v[2] = f2bf(f0.z); v[3] = f2bf(f0.w);
  v[4] = f2bf(f1.x); v[5] = f2bf(f1.y); v[6] = f2bf(f1.z); v[7] = f2bf(f1.w);
  *(short8*)(O + i) = v;
}

// ---------------------------------------------------------------------------
// 2) Projections, m97-style 128x128 tile, BK=32, global_load_lds staging.
//    Grid: 576 blocks 1D, XCD-chunked swizzle; work = which*192 + mt*6 + nt.
//    Q scaled by 0.125*log2(e) (attn works in exp2 domain).
//    K stored XOR-swizzled [bh][s][d ^ ((s&7)<<3)]
//    V stored transposed + swizzled [bh][d][s ^ ((d&7)<<3)]
// ---------------------------------------------------------------------------
__global__ __launch_bounds__(256) void proj_kernel(
    const short* __restrict__ Xb, const short* __restrict__ WTall,
    short* __restrict__ Qo, short* __restrict__ Ko, short* __restrict__ Vo) {
  int bid = blockIdx.x;
  int wk = (bid & 7) * 72 + (bid >> 3);   // 576 % 8 == 0 -> bijective
  int which = wk / 192;
  int rem = wk % 192;
  int mt = rem / 6, nt = rem % 6;
  int mbase = mt * 128, nbase = nt * 128;
  const short* X = Xb + (size_t)which * M_TOT * D_MODEL;
  const short* WT = WTall + (size_t)which * D_MODEL * D_MODEL;

  __shared__ short As[128][32];
  __shared__ short Bs[128][32];
  int tid = threadIdx.x;
  int wv = tid >> 6, lane = tid & 63, r = lane & 15, g = lane >> 4;
  int wm = (wv & 1) * 64, wn = (wv >> 1) * 64;
  int srow = (lane >> 2), scol = (lane & 3) * 8;

  f32x4 acc[4][4] = {};
  for (int kk = 0; kk < D_MODEL; kk += 32) {
#pragma unroll
    for (int j = 0; j < 2; ++j) {
      int row = wv * 32 + j * 16;
      gl16(X + (size_t)(mbase + row + srow) * D_MODEL + kk + scol, &As[row][0]);
      gl16(WT + (size_t)(nbase + row + srow) * D_MODEL + kk + scol, &Bs[row][0]);
    }
    __syncthreads();
    short8 a[4], b[4];
#pragma unroll
    for (int i = 0; i < 4; ++i) {
      a[i] = *(short8*)&As[wm + i * 16 + r][g * 8];
      b[i] = *(short8*)&Bs[wn + i * 16 + r][g * 8];
    }
#pragma unroll
    for (int i = 0; i < 4; ++i)
#pragma unroll
      for (int j = 0; j < 4; ++j)
        acc[i][j] = mfma16(a[i], b[j], acc[i][j]);
    __syncthreads();
  }
#pragma unroll
  for (int i = 0; i < 4; ++i)
#pragma unroll
    for (int j = 0; j < 4; ++j)
#pragma unroll
      for (int reg = 0; reg < 4; ++reg) {
        int m = mbase + wm + i * 16 + g * 4 + reg;
        int n = nbase + wn + j * 16 + r;
        int b_ = m >> 11, s = m & 2047, h = n >> 6, d = n & 63;
        if (which == 0) {
          short v = f2bf(acc[i][j][reg] * 0.18033688f); // 1/8 * log2(e)
          Qo[(((size_t)b_ * NH + h) * S_LEN + s) * DK + d] = v;
        } else if (which == 1) {
          short v = f2bf(acc[i][j][reg]);
          Ko[(((size_t)b_ * NH + h) * S_LEN + s) * DK + (d ^ ((s & 7) << 3))] = v;
        } else {
          short v = f2bf(acc[i][j][reg]);
          Vo[(((size_t)b_ * NH + h) * DK + d) * S_LEN + (s ^ ((d & 7) << 3))] = v;
        }
      }
}

// ---------------------------------------------------------------------------
// 3) Flash attention, m214-style: 2 waves/block, 32 q-rows/wave, KVBLK=64,
//    32x32x16 MFMA, swapped QK^T (lane-local softmax rows, exp2 domain),
//    LDS-staged K/V (double-buffered, global_load_lds, counted vmcnt),
//    cvt_pk + permlane32_swap for in-register P->A-fragment, defer-max.
// ---------------------------------------------------------------------------
__global__ __launch_bounds__(128) void attn_kernel(
    const short* __restrict__ Qg, const short* __restrict__ Kg,
    const short* __restrict__ Vt, short* __restrict__ ctx) {
  __shared__ char K_lds[2][8192];
  __shared__ char V_lds[2][8192];
  int bh = blockIdx.y;
  int b = bh / NH, h = bh % NH;
  int tid = threadIdx.x;
  int w = tid >> 6, lane = tid & 63;
  int c32 = lane & 31, hi = lane >> 5;
  int qbase = blockIdx.x * 64 + w * 32;
  const short* qp = Qg + (size_t)bh * S_LEN * DK;
  const char* kp = (const char*)(Kg + (size_t)bh * S_LEN * DK);
  const char* vp = (const char*)(Vt + (size_t)bh * DK * S_LEN);

  short8 qf[4];
#pragma unroll
  for (int kk = 0; kk < 4; ++kk)
    qf[kk] = *(const short8*)(qp + (size_t)(qbase + c32) * DK + kk * 16 + hi * 8);

#define STAGE(buf, kc)                                                          \
  {                                                                             \
    _Pragma("unroll") for (int j = 0; j < 4; ++j) {                             \
      int p = w * 4 + j;                                                        \
      gl16(kp + (size_t)(kc)*128 + p * 1024 + lane * 16, &K_lds[buf][p * 1024]);\
    }                                                                           \
    _Pragma("unroll") for (int j = 0; j < 4; ++j) {                             \
      int p = w * 4 + j;                                                        \
      int row = p * 8 + (lane >> 3);                                            \
      gl16(vp + (size_t)row * 4096 + (kc)*2 + (lane & 7) * 16,                  \
           &V_lds[buf][p * 1024]);                                              \
    }                                                                           \
  }

  STAGE(0, 0);

  f32x16 o0 = {}, o1 = {};
  float m_run = -30000.f, l_run = 0.f;
  int cur = 0;

  for (int t = 0; t < S_LEN / 64; ++t) {
    if (t < S_LEN / 64 - 1) {
      STAGE(cur ^ 1, (t + 1) * 64);
      asm volatile("s_waitcnt vmcnt(8)" ::: "memory");
    } else {
      asm volatile("s_waitcnt vmcnt(0)" ::: "memory");
    }
    __builtin_amdgcn_s_barrier();

    const char* kb = K_lds[cur];
    const char* vb = V_lds[cur];

    f32x16 st0 = {}, st1 = {};
#pragma unroll
    for (int kk = 0; kk < 4; ++kk) {
      int cb = kk * 32 + hi * 16;
      short8 k0 = *(const short8*)(kb + c32 * 128 + (cb ^ ((c32 & 7) << 4)));
      short8 k1 = *(const short8*)(kb + (32 + c32) * 128 + (cb ^ ((c32 & 7) << 4)));
      st0 = mfma32(k0, qf[kk], st0);
      st1 = mfma32(k1, qf[kk], st1);
    }

    float cm = -30000.f;
#pragma unroll
    for (int i = 0; i < 16; ++i) cm = fmaxf(cm, fmaxf(st0[i], st1[i]));
    cm = fmaxf(cm, __shfl_xor(cm, 32));
    if (!__all(cm <= m_run + 8.0f)) {
      float m_new = fmaxf(m_run, cm);
      float al = __builtin_amdgcn_exp2f(m_run - m_new);
      l_run *= al;
      m_run = m_new;
#pragma unroll
      for (int r = 0; r < 16; ++r) {
        int ql = (r & 3) + 8 * (r >> 2) + 4 * hi;
        float ar = __shfl(al, ql);
        o0[r] *= ar;
        o1[r] *= ar;
      }
    }
    float csum = 0.f;
#pragma unroll
    for (int i = 0; i < 16; ++i) {
      st0[i] = __builtin_amdgcn_exp2f(st0[i] - m_run);
      st1[i] = __builtin_amdgcn_exp2f(st1[i] - m_run);
      csum += st0[i] + st1[i];
    }
    csum += __shfl_xor(csum, 32);
    l_run += csum;

#pragma unroll
    for (int ks = 0; ks < 4; ++ks) {
      f32x16 P = (ks < 2) ? st0 : st1;
      int s8 = (ks & 1) * 8;
      unsigned A = cvtpk(P[s8 + 0], P[s8 + 1]);
      unsigned Bx = cvtpk(P[s8 + 4], P[s8 + 5]);
      unsigned C = cvtpk(P[s8 + 2], P[s8 + 3]);
      unsigned Dx = cvtpk(P[s8 + 6], P[s8 + 7]);
      plswap(A, Bx);
      plswap(C, Dx);
      union { unsigned u[4]; short8 s; } pu;
      pu.u[0] = A; pu.u[1] = C; pu.u[2] = Bx; pu.u[3] = Dx;
      int cb = ks * 32 + hi * 16;
      short8 v0 = *(const short8*)(vb + c32 * 128 + (cb ^ ((c32 & 7) << 4)));
      short8 v1 = *(const short8*)(vb + (32 + c32) * 128 + (cb ^ ((c32 & 7) << 4)));
      o0 = mfma32(pu.s, v0, o0);
      o1 = mfma32(pu.s, v1, o1);
    }

    __builtin_amdgcn_s_barrier();
    cur ^= 1;
  }

  size_t rowbase = (size_t)b * S_LEN + qbase;
#pragma unroll
  for (int r = 0; r < 16; ++r) {
    int ql = (r & 3) + 8 * (r >> 2) + 4 * hi;
    float linv = 1.0f / __shfl(l_run, ql);
    short* cp = ctx + (rowbase + ql) * D_MODEL + h * DK;
    cp[c32] = f2bf(o0[r] * linv);
    cp[32 + c32] = f2bf(o1[r] * linv);
  }
#undef STAGE
}

// ---------------------------------------------------------------------------
// 4) out = LayerNorm(ctx @ Wo + residual). One block = 16 full rows.
// ---------------------------------------------------------------------------
__global__ __launch_bounds__(256) void outln_kernel(
    const short* __restrict__ ctx, const short* __restrict__ WoT,
    const float* __restrict__ resid, float* __restrict__ out) {
  int mbase = blockIdx.x * 16;
  int tid = threadIdx.x;
  int w = tid >> 6, lane = tid & 63, r = lane & 15, g = lane >> 4;
  f32x4 acc[12] = {};
  for (int kk = 0; kk < D_MODEL; kk += 32) {
    short8 a = *(const short8*)(ctx + (size_t)(mbase + r) * D_MODEL + kk + g * 8);
#pragma unroll
    for (int j = 0; j < 12; ++j) {
      int n = w * 192 + j * 16 + r;
      short8 bv = *(const short8*)(WoT + (size_t)n * D_MODEL + kk + g * 8);
      acc[j] = mfma16(a, bv, acc[j]);
    }
  }
  __shared__ float redS[16][4];
  __shared__ float redQ[16][4];
  float ps[4], pq[4];
#pragma unroll
  for (int reg = 0; reg < 4; ++reg) {
    int m = mbase + g * 4 + reg;
    float s = 0.f, q = 0.f;
#pragma unroll
    for (int j = 0; j < 12; ++j) {
      float v = acc[j][reg] + resid[(size_t)m * D_MODEL + w * 192 + j * 16 + r];
      acc[j][reg] = v;
      s += v;
      q += v * v;
    }
    ps[reg] = s; pq[reg] = q;
  }
#pragma unroll
  for (int reg = 0; reg < 4; ++reg) {
    float s = ps[reg], q = pq[reg];
    s += __shfl_xor(s, 1); q += __shfl_xor(q, 1);
    s += __shfl_xor(s, 2); q += __shfl_xor(q, 2);
    s += __shfl_xor(s, 4); q += __shfl_xor(q, 4);
    s += __shfl_xor(s, 8); q += __shfl_xor(q, 8);
    if (r == 0) { redS[g * 4 + reg][w] = s; redQ[g * 4 + reg][w] = q; }
  }
  __syncthreads();
#pragma unroll
  for (int reg = 0; reg < 4; ++reg) {
    int row = g * 4 + reg;
    float s = redS[row][0] + redS[row][1] + redS[row][2] + redS[row][3];
    float q = redQ[row][0] + redQ[row][1] + redQ[row][2] + redQ[row][3];
    float mu = s * (1.0f / 768.0f);
    float var = q * (1.0f / 768.0f) - mu * mu;
    float rstd = rsqrtf(var + 1e-5f);
    int m = mbase + row;
#pragma unroll
    for (int j = 0; j < 12; ++j)
      out[(size_t)m * D_MODEL + w * 192 + j * 16 + r] = (acc[j][reg] - mu) * rstd;
  }
}

// ---------------------------------------------------------------------------
extern "C" void kernel_launch(void* const* d_in, const int* in_sizes, int n_in,
                              void* d_out, int out_size, void* d_ws, size_t ws_size,
                              hipStream_t stream) {
  const float* xq = (const float*)d_in[0];
  const float* xk = (const float*)d_in[1];
  const float* xv = (const float*)d_in[2];
  const float* Wq = (const float*)d_in[3];
  const float* Wk = (const float*)d_in[4];
  const float* Wv = (const float*)d_in[5];
  const float* Wo = (const float*)d_in[6];
  float* out = (float*)d_out;

  char* ws = (char*)d_ws;
  const size_t WSZ = (size_t)D_MODEL * D_MODEL;   // 589824
  const size_t QSZ = (size_t)M_TOT * D_MODEL;     // 3145728
  short* WT = (short*)ws;                         // 4 * WSZ
  short* Xb = WT + 4 * WSZ;                       // 3 * QSZ (bf16 activations)
  short* Qb = Xb + 3 * QSZ;
  short* Kb = Qb + QSZ;
  short* Vb = Kb + QSZ;
  short* Cx = Vb + QSZ;

  transpose_w_kernel<<<dim3(24, 24, 4), dim3(32, 8), 0, stream>>>(Wq, Wk, Wv, Wo, WT);
  cast_x_kernel<<<dim3(1536, 3), 256, 0, stream>>>(xq, xk, xv, Xb);
  proj_kernel<<<576, 256, 0, stream>>>(Xb, WT, Qb, Kb, Vb);
  attn_kernel<<<dim3(32, 24), 128, 0, stream>>>(Qb, Kb, Vb, Cx);
  outln_kernel<<<dim3(256), 256, 0, stream>>>(Cx, WT + 3 * WSZ, xq, out);
}

// Round 4
// 226.017 us; speedup vs baseline: 1.7672x; 1.1924x over previous
//
#include <hip/hip_runtime.h>
#include <hip/hip_bf16.h>
#include <stdint.h>

#define S_LEN 2048
#define D_MODEL 768
#define NH 12
#define DK 64
#define BATCH 2
#define M_TOT (BATCH * S_LEN) /* 4096 */

typedef __attribute__((ext_vector_type(8))) short short8;
typedef __attribute__((ext_vector_type(4))) float f32x4;
typedef __attribute__((ext_vector_type(16))) float f32x16;

__device__ inline short f2bf(float f) {
  union { float f; uint32_t u; } v; v.f = f;
  uint32_t r = v.u + 0x7fffu + ((v.u >> 16) & 1u);
  return (short)(r >> 16);
}

__device__ inline f32x4 mfma16(short8 a, short8 b, f32x4 c) {
  return __builtin_amdgcn_mfma_f32_16x16x32_bf16(a, b, c, 0, 0, 0);
}
__device__ inline f32x16 mfma32(short8 a, short8 b, f32x16 c) {
  return __builtin_amdgcn_mfma_f32_32x32x16_bf16(a, b, c, 0, 0, 0);
}

__device__ inline void gl16(const void* g, void* l) {
  __builtin_amdgcn_global_load_lds(
      (const __attribute__((address_space(1))) unsigned*)g,
      (__attribute__((address_space(3))) unsigned*)l, 16, 0, 0);
}

__device__ inline unsigned cvtpk(float lo, float hi) {
  unsigned r;
  asm("v_cvt_pk_bf16_f32 %0, %1, %2" : "=v"(r) : "v"(lo), "v"(hi));
  return r;
}
__device__ inline void plswap(unsigned& a, unsigned& b) {
  asm("v_permlane32_swap_b32 %0, %1" : "+v"(a), "+v"(b));
}

// ---------------------------------------------------------------------------
// 1a) Weight transpose + bf16 cast (all 4 weights in one launch, z selects)
// ---------------------------------------------------------------------------
__global__ __launch_bounds__(256) void transpose_w_kernel(
    const float* __restrict__ Wq, const float* __restrict__ Wk,
    const float* __restrict__ Wv, const float* __restrict__ Wo,
    short* __restrict__ WT) {
  int z = blockIdx.z;
  const float* W = z == 0 ? Wq : (z == 1 ? Wk : (z == 2 ? Wv : Wo));
  short* O = WT + (size_t)z * D_MODEL * D_MODEL;
  __shared__ float t[32][33];
  int x = threadIdx.x, y = threadIdx.y;
  int nb = blockIdx.x * 32, kb = blockIdx.y * 32;
#pragma unroll
  for (int j = 0; j < 4; ++j)
    t[y + 8 * j][x] = W[(kb + y + 8 * j) * D_MODEL + nb + x];
  __syncthreads();
#pragma unroll
  for (int j = 0; j < 4; ++j)
    O[(nb + y + 8 * j) * D_MODEL + kb + x] = f2bf(t[x][y + 8 * j]);
}

// ---------------------------------------------------------------------------
// 1b) Activation cast fp32 -> bf16 (one pass; removes 12x fp32 re-fetch)
// ---------------------------------------------------------------------------
__global__ __launch_bounds__(256) void cast_x_kernel(
    const float* __restrict__ Xq, const float* __restrict__ Xk,
    const float* __restrict__ Xv, short* __restrict__ Xb) {
  int z = blockIdx.y;
  const float* X = z == 0 ? Xq : (z == 1 ? Xk : Xv);
  short* O = Xb + (size_t)z * M_TOT * D_MODEL;
  size_t i = ((size_t)blockIdx.x * 256 + threadIdx.x) * 8;
  float4 f0 = *(const float4*)(X + i);
  float4 f1 = *(const float4*)(X + i + 4);
  short8 v;
  v[0] = f2bf(f0.x); v[1] = f2bf(f0.y); v[2] = f2bf(f0.z); v[3] = f2bf(f0.w);
  v[4] = f2bf(f1.x); v[5] = f2bf(f1.y); v[6] = f2bf(f1.z); v[7] = f2bf(f1.w);
  *(short8*)(O + i) = v;
}

// ---------------------------------------------------------------------------
// 2) Projections, m97-style 128x128 tile, BK=32, global_load_lds staging.
// ---------------------------------------------------------------------------
__global__ __launch_bounds__(256) void proj_kernel(
    const short* __restrict__ Xb, const short* __restrict__ WTall,
    short* __restrict__ Qo, short* __restrict__ Ko, short* __restrict__ Vo) {
  int bid = blockIdx.x;
  int wk = (bid & 7) * 72 + (bid >> 3);   // 576 % 8 == 0 -> bijective
  int which = wk / 192;
  int rem = wk % 192;
  int mt = rem / 6, nt = rem % 6;
  int mbase = mt * 128, nbase = nt * 128;
  const short* X = Xb + (size_t)which * M_TOT * D_MODEL;
  const short* WT = WTall + (size_t)which * D_MODEL * D_MODEL;

  __shared__ short As[128][32];
  __shared__ short Bs[128][32];
  int tid = threadIdx.x;
  int wv = tid >> 6, lane = tid & 63, r = lane & 15, g = lane >> 4;
  int wm = (wv & 1) * 64, wn = (wv >> 1) * 64;
  int srow = (lane >> 2), scol = (lane & 3) * 8;

  f32x4 acc[4][4] = {};
  for (int kk = 0; kk < D_MODEL; kk += 32) {
#pragma unroll
    for (int j = 0; j < 2; ++j) {
      int row = wv * 32 + j * 16;
      gl16(X + (size_t)(mbase + row + srow) * D_MODEL + kk + scol, &As[row][0]);
      gl16(WT + (size_t)(nbase + row + srow) * D_MODEL + kk + scol, &Bs[row][0]);
    }
    __syncthreads();
    short8 a[4], b[4];
#pragma unroll
    for (int i = 0; i < 4; ++i) {
      a[i] = *(short8*)&As[wm + i * 16 + r][g * 8];
      b[i] = *(short8*)&Bs[wn + i * 16 + r][g * 8];
    }
#pragma unroll
    for (int i = 0; i < 4; ++i)
#pragma unroll
      for (int j = 0; j < 4; ++j)
        acc[i][j] = mfma16(a[i], b[j], acc[i][j]);
    __syncthreads();
  }
#pragma unroll
  for (int i = 0; i < 4; ++i)
#pragma unroll
    for (int j = 0; j < 4; ++j)
#pragma unroll
      for (int reg = 0; reg < 4; ++reg) {
        int m = mbase + wm + i * 16 + g * 4 + reg;
        int n = nbase + wn + j * 16 + r;
        int b_ = m >> 11, s = m & 2047, h = n >> 6, d = n & 63;
        if (which == 0) {
          short v = f2bf(acc[i][j][reg] * 0.18033688f); // 1/8 * log2(e)
          Qo[(((size_t)b_ * NH + h) * S_LEN + s) * DK + d] = v;
        } else if (which == 1) {
          short v = f2bf(acc[i][j][reg]);
          Ko[(((size_t)b_ * NH + h) * S_LEN + s) * DK + (d ^ ((s & 7) << 3))] = v;
        } else {
          short v = f2bf(acc[i][j][reg]);
          Vo[(((size_t)b_ * NH + h) * DK + d) * S_LEN + (s ^ ((d & 7) << 3))] = v;
        }
      }
}

// ---------------------------------------------------------------------------
// 3) Flash attention, m214-style (unchanged from round 2).
// ---------------------------------------------------------------------------
__global__ __launch_bounds__(128) void attn_kernel(
    const short* __restrict__ Qg, const short* __restrict__ Kg,
    const short* __restrict__ Vt, short* __restrict__ ctx) {
  __shared__ char K_lds[2][8192];
  __shared__ char V_lds[2][8192];
  int bh = blockIdx.y;
  int b = bh / NH, h = bh % NH;
  int tid = threadIdx.x;
  int w = tid >> 6, lane = tid & 63;
  int c32 = lane & 31, hi = lane >> 5;
  int qbase = blockIdx.x * 64 + w * 32;
  const short* qp = Qg + (size_t)bh * S_LEN * DK;
  const char* kp = (const char*)(Kg + (size_t)bh * S_LEN * DK);
  const char* vp = (const char*)(Vt + (size_t)bh * DK * S_LEN);

  short8 qf[4];
#pragma unroll
  for (int kk = 0; kk < 4; ++kk)
    qf[kk] = *(const short8*)(qp + (size_t)(qbase + c32) * DK + kk * 16 + hi * 8);

#define STAGE(buf, kc)                                                          \
  {                                                                             \
    _Pragma("unroll") for (int j = 0; j < 4; ++j) {                             \
      int p = w * 4 + j;                                                        \
      gl16(kp + (size_t)(kc)*128 + p * 1024 + lane * 16, &K_lds[buf][p * 1024]);\
    }                                                                           \
    _Pragma("unroll") for (int j = 0; j < 4; ++j) {                             \
      int p = w * 4 + j;                                                        \
      int row = p * 8 + (lane >> 3);                                            \
      gl16(vp + (size_t)row * 4096 + (kc)*2 + (lane & 7) * 16,                  \
           &V_lds[buf][p * 1024]);                                              \
    }                                                                           \
  }

  STAGE(0, 0);

  f32x16 o0 = {}, o1 = {};
  float m_run = -30000.f, l_run = 0.f;
  int cur = 0;

  for (int t = 0; t < S_LEN / 64; ++t) {
    if (t < S_LEN / 64 - 1) {
      STAGE(cur ^ 1, (t + 1) * 64);
      asm volatile("s_waitcnt vmcnt(8)" ::: "memory");
    } else {
      asm volatile("s_waitcnt vmcnt(0)" ::: "memory");
    }
    __builtin_amdgcn_s_barrier();

    const char* kb = K_lds[cur];
    const char* vb = V_lds[cur];

    f32x16 st0 = {}, st1 = {};
#pragma unroll
    for (int kk = 0; kk < 4; ++kk) {
      int cb = kk * 32 + hi * 16;
      short8 k0 = *(const short8*)(kb + c32 * 128 + (cb ^ ((c32 & 7) << 4)));
      short8 k1 = *(const short8*)(kb + (32 + c32) * 128 + (cb ^ ((c32 & 7) << 4)));
      st0 = mfma32(k0, qf[kk], st0);
      st1 = mfma32(k1, qf[kk], st1);
    }

    float cm = -30000.f;
#pragma unroll
    for (int i = 0; i < 16; ++i) cm = fmaxf(cm, fmaxf(st0[i], st1[i]));
    cm = fmaxf(cm, __shfl_xor(cm, 32));
    if (!__all(cm <= m_run + 8.0f)) {
      float m_new = fmaxf(m_run, cm);
      float al = __builtin_amdgcn_exp2f(m_run - m_new);
      l_run *= al;
      m_run = m_new;
#pragma unroll
      for (int r = 0; r < 16; ++r) {
        int ql = (r & 3) + 8 * (r >> 2) + 4 * hi;
        float ar = __shfl(al, ql);
        o0[r] *= ar;
        o1[r] *= ar;
      }
    }
    float csum = 0.f;
#pragma unroll
    for (int i = 0; i < 16; ++i) {
      st0[i] = __builtin_amdgcn_exp2f(st0[i] - m_run);
      st1[i] = __builtin_amdgcn_exp2f(st1[i] - m_run);
      csum += st0[i] + st1[i];
    }
    csum += __shfl_xor(csum, 32);
    l_run += csum;

#pragma unroll
    for (int ks = 0; ks < 4; ++ks) {
      f32x16 P = (ks < 2) ? st0 : st1;
      int s8 = (ks & 1) * 8;
      unsigned A = cvtpk(P[s8 + 0], P[s8 + 1]);
      unsigned Bx = cvtpk(P[s8 + 4], P[s8 + 5]);
      unsigned C = cvtpk(P[s8 + 2], P[s8 + 3]);
      unsigned Dx = cvtpk(P[s8 + 6], P[s8 + 7]);
      plswap(A, Bx);
      plswap(C, Dx);
      union { unsigned u[4]; short8 s; } pu;
      pu.u[0] = A; pu.u[1] = C; pu.u[2] = Bx; pu.u[3] = Dx;
      int cb = ks * 32 + hi * 16;
      short8 v0 = *(const short8*)(vb + c32 * 128 + (cb ^ ((c32 & 7) << 4)));
      short8 v1 = *(const short8*)(vb + (32 + c32) * 128 + (cb ^ ((c32 & 7) << 4)));
      o0 = mfma32(pu.s, v0, o0);
      o1 = mfma32(pu.s, v1, o1);
    }

    __builtin_amdgcn_s_barrier();
    cur ^= 1;
  }

  size_t rowbase = (size_t)b * S_LEN + qbase;
#pragma unroll
  for (int r = 0; r < 16; ++r) {
    int ql = (r & 3) + 8 * (r >> 2) + 4 * hi;
    float linv = 1.0f / __shfl(l_run, ql);
    short* cp = ctx + (rowbase + ql) * D_MODEL + h * DK;
    cp[c32] = f2bf(o0[r] * linv);
    cp[32 + c32] = f2bf(o1[r] * linv);
  }
#undef STAGE
}

// ---------------------------------------------------------------------------
// 4a) Y = ctx @ Wo + resid  (f32 out). Same 128x128 m97 structure as proj.
// ---------------------------------------------------------------------------
__global__ __launch_bounds__(256) void gemm_out_kernel(
    const short* __restrict__ ctx, const short* __restrict__ WoT,
    const float* __restrict__ resid, float* __restrict__ Y) {
  int bid = blockIdx.x;
  int wk = (bid & 7) * 24 + (bid >> 3);   // 192 % 8 == 0 -> bijective
  int mt = wk / 6, nt = wk % 6;
  int mbase = mt * 128, nbase = nt * 128;

  __shared__ short As[128][32];
  __shared__ short Bs[128][32];
  int tid = threadIdx.x;
  int wv = tid >> 6, lane = tid & 63, r = lane & 15, g = lane >> 4;
  int wm = (wv & 1) * 64, wn = (wv >> 1) * 64;
  int srow = (lane >> 2), scol = (lane & 3) * 8;

  f32x4 acc[4][4] = {};
  for (int kk = 0; kk < D_MODEL; kk += 32) {
#pragma unroll
    for (int j = 0; j < 2; ++j) {
      int row = wv * 32 + j * 16;
      gl16(ctx + (size_t)(mbase + row + srow) * D_MODEL + kk + scol, &As[row][0]);
      gl16(WoT + (size_t)(nbase + row + srow) * D_MODEL + kk + scol, &Bs[row][0]);
    }
    __syncthreads();
    short8 a[4], b[4];
#pragma unroll
    for (int i = 0; i < 4; ++i) {
      a[i] = *(short8*)&As[wm + i * 16 + r][g * 8];
      b[i] = *(short8*)&Bs[wn + i * 16 + r][g * 8];
    }
#pragma unroll
    for (int i = 0; i < 4; ++i)
#pragma unroll
      for (int j = 0; j < 4; ++j)
        acc[i][j] = mfma16(a[i], b[j], acc[i][j]);
    __syncthreads();
  }
#pragma unroll
  for (int i = 0; i < 4; ++i)
#pragma unroll
    for (int j = 0; j < 4; ++j)
#pragma unroll
      for (int reg = 0; reg < 4; ++reg) {
        int m = mbase + wm + i * 16 + g * 4 + reg;
        int n = nbase + wn + j * 16 + r;
        Y[(size_t)m * D_MODEL + n] = acc[i][j][reg] + resid[(size_t)m * D_MODEL + n];
      }
}

// ---------------------------------------------------------------------------
// 4b) LayerNorm over Y rows (wave per row). Y already includes residual.
// ---------------------------------------------------------------------------
__global__ __launch_bounds__(256) void ln_kernel(const float* __restrict__ Y,
                                                 float* __restrict__ out) {
  int row = blockIdx.x * 4 + (threadIdx.x >> 6);
  int l = threadIdx.x & 63;
  const float* yp = Y + (size_t)row * D_MODEL;
  float v[12];
  float s = 0.f, q = 0.f;
#pragma unroll
  for (int c = 0; c < 12; ++c) {
    v[c] = yp[c * 64 + l];
    s += v[c];
    q += v[c] * v[c];
  }
#pragma unroll
  for (int d = 1; d < 64; d <<= 1) {
    s += __shfl_xor(s, d);
    q += __shfl_xor(q, d);
  }
  float mu = s * (1.0f / 768.0f);
  float var = q * (1.0f / 768.0f) - mu * mu;
  float rstd = rsqrtf(var + 1e-5f);
  float* op = out + (size_t)row * D_MODEL;
#pragma unroll
  for (int c = 0; c < 12; ++c)
    op[c * 64 + l] = (v[c] - mu) * rstd;
}

// ---------------------------------------------------------------------------
extern "C" void kernel_launch(void* const* d_in, const int* in_sizes, int n_in,
                              void* d_out, int out_size, void* d_ws, size_t ws_size,
                              hipStream_t stream) {
  const float* xq = (const float*)d_in[0];
  const float* xk = (const float*)d_in[1];
  const float* xv = (const float*)d_in[2];
  const float* Wq = (const float*)d_in[3];
  const float* Wk = (const float*)d_in[4];
  const float* Wv = (const float*)d_in[5];
  const float* Wo = (const float*)d_in[6];
  float* out = (float*)d_out;

  char* ws = (char*)d_ws;
  const size_t WSZ = (size_t)D_MODEL * D_MODEL;   // 589824
  const size_t QSZ = (size_t)M_TOT * D_MODEL;     // 3145728
  short* WT = (short*)ws;                         // 4 * WSZ
  short* Xb = WT + 4 * WSZ;                       // 3 * QSZ (bf16 activations)
  short* Qb = Xb + 3 * QSZ;
  short* Kb = Qb + QSZ;
  short* Vb = Kb + QSZ;
  short* Cx = Vb + QSZ;
  float* Yf = (float*)Xb;  // alias: Xb dead after proj_kernel; 12.6MB < 18.9MB

  transpose_w_kernel<<<dim3(24, 24, 4), dim3(32, 8), 0, stream>>>(Wq, Wk, Wv, Wo, WT);
  cast_x_kernel<<<dim3(1536, 3), 256, 0, stream>>>(xq, xk, xv, Xb);
  proj_kernel<<<576, 256, 0, stream>>>(Xb, WT, Qb, Kb, Vb);
  attn_kernel<<<dim3(32, 24), 128, 0, stream>>>(Qb, Kb, Vb, Cx);
  gemm_out_kernel<<<192, 256, 0, stream>>>(Cx, WT + 3 * WSZ, xq, Yf);
  ln_kernel<<<1024, 256, 0, stream>>>(Yf, out);
}